// Round 2
// baseline (1050.182 us; speedup 1.0000x reference)
//
#include <hip/hip_runtime.h>
#include <hip/hip_bf16.h>
#include <stdint.h>

// B=512 L=32 E=2048 H=32 D=64 ; M = B*L = 16384 ; K = 2048 ; Nqkv = 6144
typedef __bf16 bf16x8 __attribute__((ext_vector_type(8)));
typedef float f32x4 __attribute__((ext_vector_type(4)));
typedef unsigned short u16x8 __attribute__((ext_vector_type(8)));
typedef unsigned short u16x4 __attribute__((ext_vector_type(4)));

#define G_AS __attribute__((address_space(1)))
#define L_AS __attribute__((address_space(3)))

__device__ __forceinline__ void gload_lds16(const void* g, void* l) {
  __builtin_amdgcn_global_load_lds((G_AS void*)g, (L_AS void*)l, 16, 0, 0);
}

__device__ __forceinline__ float b2f(unsigned short u) {
  union { float f; unsigned int i; } cv;
  cv.i = ((unsigned int)u) << 16;
  return cv.f;
}

__device__ __forceinline__ unsigned short f2b(float f) {
  unsigned int u = __float_as_uint(f);
  unsigned int r = u + 0x7FFFu + ((u >> 16) & 1u);  // RNE (inputs are non-NaN)
  return (unsigned short)(r >> 16);
}

// ---------------- cast / pack kernels ----------------

__global__ void k_cast_f32_bf16(const float* __restrict__ src,
                                unsigned short* __restrict__ dst, int n4) {
  int i = blockIdx.x * blockDim.x + threadIdx.x;
  if (i >= n4) return;
  float4 v = reinterpret_cast<const float4*>(src)[i];
  u16x4 o;
  o[0] = f2b(v.x); o[1] = f2b(v.y); o[2] = f2b(v.z); o[3] = f2b(v.w);
  reinterpret_cast<u16x4*>(dst)[i] = o;
}

// wqkvb rows: [0,2048)=wq, [2048,4096)=wk*0.125 (folds softmax scale), [4096,6144)=wv
__global__ void k_build_wqkv(const float* __restrict__ wq, const float* __restrict__ wk,
                             const float* __restrict__ wv, unsigned short* __restrict__ dst) {
  int i = blockIdx.x * blockDim.x + threadIdx.x;  // 6144*2048/4 = 3145728 threads
  if (i >= 3145728) return;
  int e = i << 2;
  int row = e >> 11;
  int col = e & 2047;
  const float* src; float sc = 1.0f;
  if (row < 2048) { src = wq + ((size_t)row << 11); }
  else if (row < 4096) { src = wk + ((size_t)(row - 2048) << 11); sc = 0.125f; }
  else { src = wv + ((size_t)(row - 4096) << 11); }
  float4 v = *reinterpret_cast<const float4*>(src + col);
  u16x4 o;
  o[0] = f2b(v.x * sc); o[1] = f2b(v.y * sc); o[2] = f2b(v.z * sc); o[3] = f2b(v.w * sc);
  *reinterpret_cast<u16x4*>(dst + e) = o;
}

__global__ void k_build_bqkv(const float* __restrict__ bq, const float* __restrict__ bk,
                             const float* __restrict__ bv, float* __restrict__ dst) {
  int i = blockIdx.x * blockDim.x + threadIdx.x;
  if (i >= 6144) return;
  float v;
  if (i < 2048) v = bq[i];
  else if (i < 4096) v = bk[i - 2048] * 0.125f;
  else v = bv[i - 4096];
  dst[i] = v;
}

// relb[h][j][d] = rpe[h - j + 31][d]   (faithful to the reference's H==L broadcast quirk)
__global__ void k_build_rel(const float* __restrict__ rpe, unsigned short* __restrict__ dst) {
  int i = blockIdx.x * blockDim.x + threadIdx.x;  // 32*32*16 = 16384
  if (i >= 16384) return;
  int h = i >> 9;
  int j = (i >> 4) & 31;
  int d = (i & 15) << 2;
  const float* s = rpe + (size_t)(h - j + 31) * 64 + d;
  float4 v = *reinterpret_cast<const float4*>(s);
  u16x4 o;
  o[0] = f2b(v.x); o[1] = f2b(v.y); o[2] = f2b(v.z); o[3] = f2b(v.w);
  *reinterpret_cast<u16x4*>(dst + ((size_t)i << 2)) = o;
}

// ---------------- GEMM: C[M][N] = A[M][K] * B[N][K]^T + bias[N] ----------------
// 256x256 tile, BK=32, 8 waves (2Mx4N), 512 threads, 4-deep LDS pipeline (128 KiB),
// counted vmcnt(12) (never 0 in main loop), conflict-free chunked LDS layout,
// setprio around MFMA cluster, bijective XCD swizzle (grid % 8 == 0).
//
// LDS tile layout (per 16 KiB buffer, per matrix): 16B chunk for (row, slot) lives at
//   phys = (row>>3)*32 + slot*8 + (row&7)        (slot = k-subcol/8, 4 slots of 8 bf16)
// Read: quarter-wave (16 lanes, rows r0..r0+15, fixed slot) covers all 32 banks 2x -> free.
// Write: global_load_lds dest is LINEAR in chunk index; the permutation is applied to the
// per-lane GLOBAL source address (rule: linear dest + permuted source + permuted read).

template <int OUT_F32>
__global__ __launch_bounds__(512, 2)
void k_gemm256(const unsigned short* __restrict__ A,
               const unsigned short* __restrict__ B,
               const float* __restrict__ bias,
               void* __restrict__ Cptr,
               int M, int N, int K)
{
  __shared__ __align__(16) unsigned short As[4][8192];
  __shared__ __align__(16) unsigned short Bs[4][8192];

  // bijective XCD swizzle (grid divisible by 8), column-major block order
  const int bmCnt = M >> 8;
  const int cpx = gridDim.x >> 3;
  const int orig = blockIdx.x;
  const int wg = (orig & 7) * cpx + (orig >> 3);
  const int bn = wg / bmCnt;
  const int bm = wg % bmCnt;

  const int tid = threadIdx.x;
  const int lane = tid & 63;
  const int wid = tid >> 6;
  const int wr = wid >> 2;   // 0..1
  const int wc = wid & 3;    // 0..3

  // ---- staging: per thread 2 chunks per matrix per K-tile ----
  // chunk c (0..1023): row = ((c>>5)<<3)+(c&7), colOff = ((c>>3)&3)*8 ; c1 = c0+512 -> row+128
  const int c0 = wid * 64 + lane;                 // 0..511, lds addr = base + lane*16
  const int rs = ((c0 >> 5) << 3) + (c0 & 7);
  const int cs = ((c0 >> 3) & 3) << 3;
  const unsigned short* agA0 = A + (size_t)(bm * 256 + rs) * K + cs;
  const unsigned short* agA1 = agA0 + (size_t)128 * K;
  const unsigned short* agB0 = B + (size_t)(bn * 256 + rs) * K + cs;
  const unsigned short* agB1 = agB0 + (size_t)128 * K;
  const int l0 = c0 * 8;          // ushort index of chunk c0 (byte = c0*16)
  const int l1 = c0 * 8 + 4096;   // chunk c0+512

  // ---- fragment read bases (ushort index inside a 8192-ushort buffer) ----
  const int fr = lane & 15;
  const int sl = lane >> 4;                                 // k slot 0..3
  const int rb = ((fr >> 3) << 8) + (sl << 6) + ((fr & 7) << 3);
  const int aOff = wr * 4096 + rb;                          // + m*512, m=0..7
  const int bOff = wc * 2048 + rb;                          // + n*512, n=0..3

  f32x4 acc[8][4] = {};
  const int NT = K >> 5;  // BK=32

  // prologue: stage tiles 0..2 into bufs 0..2
#pragma unroll
  for (int pf = 0; pf < 3; ++pf) {
    const int kof = pf << 5;
    gload_lds16(agA0 + kof, &As[pf][l0]);
    gload_lds16(agA1 + kof, &As[pf][l1]);
    gload_lds16(agB0 + kof, &Bs[pf][l0]);
    gload_lds16(agB1 + kof, &Bs[pf][l1]);
  }

  for (int t = 0; t < NT; ++t) {
    const int pf = t + 3;
    if (pf < NT) {
      const int buf = pf & 3;      // provably disjoint from read buf t&3
      const int kof = pf << 5;
      gload_lds16(agA0 + kof, &As[buf][l0]);
      gload_lds16(agA1 + kof, &As[buf][l1]);
      gload_lds16(agB0 + kof, &Bs[buf][l0]);
      gload_lds16(agB1 + kof, &Bs[buf][l1]);
    }
    // counted wait: tile t's 4 loads/thread landed when <= 12 (3 tiles) outstanding
    if (t + 3 < NT)      asm volatile("s_waitcnt vmcnt(12)" ::: "memory");
    else if (t + 2 < NT) asm volatile("s_waitcnt vmcnt(8)" ::: "memory");
    else if (t + 1 < NT) asm volatile("s_waitcnt vmcnt(4)" ::: "memory");
    else                 asm volatile("s_waitcnt vmcnt(0)" ::: "memory");
    __builtin_amdgcn_s_barrier();          // all waves' tile-t DMA landed
    __builtin_amdgcn_sched_barrier(0);

    const unsigned short* ab = &As[t & 3][0];
    const unsigned short* bb = &Bs[t & 3][0];
    bf16x8 bfv[4], afv[8];
#pragma unroll
    for (int n = 0; n < 4; ++n)
      bfv[n] = *reinterpret_cast<const bf16x8*>(bb + bOff + n * 512);
#pragma unroll
    for (int m = 0; m < 8; ++m)
      afv[m] = *reinterpret_cast<const bf16x8*>(ab + aOff + m * 512);
    __builtin_amdgcn_s_setprio(1);
#pragma unroll
    for (int m = 0; m < 8; ++m)
#pragma unroll
      for (int n = 0; n < 4; ++n)
        acc[m][n] = __builtin_amdgcn_mfma_f32_16x16x32_bf16(afv[m], bfv[n], acc[m][n], 0, 0, 0);
    __builtin_amdgcn_s_setprio(0);
    __builtin_amdgcn_sched_barrier(0);
    __builtin_amdgcn_s_barrier();          // all reads of buf t&3 done -> next iter may overwrite
  }

  // epilogue: C/D layout col = lane&15, row = (lane>>4)*4 + reg
  const int rBase = bm * 256 + wr * 128 + (sl << 2);
  const int cBase = bn * 256 + wc * 64 + fr;
#pragma unroll
  for (int n = 0; n < 4; ++n) {
    const int col = cBase + n * 16;
    const float bv = bias[col];
#pragma unroll
    for (int m = 0; m < 8; ++m) {
      const int row = rBase + m * 16;
#pragma unroll
      for (int r = 0; r < 4; ++r) {
        float v = acc[m][n][r] + bv;
        if (OUT_F32) {
          reinterpret_cast<float*>(Cptr)[(size_t)(row + r) * N + col] = v;
        } else {
          reinterpret_cast<unsigned short*>(Cptr)[(size_t)(row + r) * N + col] = f2b(v);
        }
      }
    }
  }
}

// ---------------- attention: one block (256 thr) per (b,h) ----------------
// qkv row-major [16384][6144]; q at col h*64, k(prescaled) at 2048+h*64, v at 4096+h*64
// S[i][j] = sum_d q[i,d]*(k_s[j,d] + rel[h,j,d]) ; softmax over j ; ctx = P·V

__global__ __launch_bounds__(256)
void k_attn(const unsigned short* __restrict__ qkv,
            const unsigned short* __restrict__ relb,
            unsigned short* __restrict__ ctx)
{
  __shared__ float qL[32][68];
  __shared__ float krL[32][68];
  __shared__ float vL[32][68];
  __shared__ float SL[32][33];

  const int bh = blockIdx.x;
  const int b = bh >> 5;
  const int h = bh & 31;
  const int t = threadIdx.x;
  const int r = t >> 3;           // row 0..31
  const int d0 = (t & 7) << 3;    // d 0..56 step 8

  const unsigned short* base = qkv + (size_t)(b * 32 + r) * 6144 + h * 64 + d0;
  u16x8 uq = *reinterpret_cast<const u16x8*>(base);
  u16x8 uk = *reinterpret_cast<const u16x8*>(base + 2048);
  u16x8 uv = *reinterpret_cast<const u16x8*>(base + 4096);
  u16x8 ur = *reinterpret_cast<const u16x8*>(relb + (((size_t)(h * 32 + r)) << 6) + d0);

  float fq[8], fkr[8], fv[8];
#pragma unroll
  for (int c = 0; c < 8; ++c) {
    fq[c] = b2f(uq[c]);
    fkr[c] = b2f(uk[c]) + b2f(ur[c]);
    fv[c] = b2f(uv[c]);
  }
  *reinterpret_cast<float4*>(&qL[r][d0])      = make_float4(fq[0], fq[1], fq[2], fq[3]);
  *reinterpret_cast<float4*>(&qL[r][d0 + 4])  = make_float4(fq[4], fq[5], fq[6], fq[7]);
  *reinterpret_cast<float4*>(&krL[r][d0])     = make_float4(fkr[0], fkr[1], fkr[2], fkr[3]);
  *reinterpret_cast<float4*>(&krL[r][d0 + 4]) = make_float4(fkr[4], fkr[5], fkr[6], fkr[7]);
  *reinterpret_cast<float4*>(&vL[r][d0])      = make_float4(fv[0], fv[1], fv[2], fv[3]);
  *reinterpret_cast<float4*>(&vL[r][d0 + 4])  = make_float4(fv[4], fv[5], fv[6], fv[7]);
  __syncthreads();

  const int i = r;
  const int j0 = (t & 7) << 2;   // 4 score cols per thread
  float s0 = 0.f, s1 = 0.f, s2 = 0.f, s3 = 0.f;
#pragma unroll
  for (int d = 0; d < 64; d += 4) {
    float4 qv = *reinterpret_cast<const float4*>(&qL[i][d]);
    float4 k0 = *reinterpret_cast<const float4*>(&krL[j0 + 0][d]);
    float4 k1 = *reinterpret_cast<const float4*>(&krL[j0 + 1][d]);
    float4 k2 = *reinterpret_cast<const float4*>(&krL[j0 + 2][d]);
    float4 k3 = *reinterpret_cast<const float4*>(&krL[j0 + 3][d]);
    s0 += qv.x * k0.x + qv.y * k0.y + qv.z * k0.z + qv.w * k0.w;
    s1 += qv.x * k1.x + qv.y * k1.y + qv.z * k1.z + qv.w * k1.w;
    s2 += qv.x * k2.x + qv.y * k2.y + qv.z * k2.z + qv.w * k2.w;
    s3 += qv.x * k3.x + qv.y * k3.y + qv.z * k3.z + qv.w * k3.w;
  }
  SL[i][j0 + 0] = s0; SL[i][j0 + 1] = s1; SL[i][j0 + 2] = s2; SL[i][j0 + 3] = s3;
  __syncthreads();

  float m = SL[i][0];
#pragma unroll
  for (int jj = 1; jj < 32; ++jj) m = fmaxf(m, SL[i][jj]);
  __syncthreads();  // all max reads done before P overwrites S

  float p0 = __expf(s0 - m), p1 = __expf(s1 - m), p2 = __expf(s2 - m), p3 = __expf(s3 - m);
  SL[i][j0 + 0] = p0; SL[i][j0 + 1] = p1; SL[i][j0 + 2] = p2; SL[i][j0 + 3] = p3;
  __syncthreads();

  float den = 0.f;
#pragma unroll
  for (int jj = 0; jj < 32; ++jj) den += SL[i][jj];
  const float inv = 1.0f / den;

  float o[8] = {0.f, 0.f, 0.f, 0.f, 0.f, 0.f, 0.f, 0.f};
#pragma unroll
  for (int jj = 0; jj < 32; ++jj) {
    float pj = SL[i][jj];
    float4 v0 = *reinterpret_cast<const float4*>(&vL[jj][d0]);
    float4 v1 = *reinterpret_cast<const float4*>(&vL[jj][d0 + 4]);
    o[0] += pj * v0.x; o[1] += pj * v0.y; o[2] += pj * v0.z; o[3] += pj * v0.w;
    o[4] += pj * v1.x; o[5] += pj * v1.y; o[6] += pj * v1.z; o[7] += pj * v1.w;
  }
  u16x8 ov;
#pragma unroll
  for (int c = 0; c < 8; ++c) ov[c] = f2b(o[c] * inv);
  *reinterpret_cast<u16x8*>(ctx + (size_t)(b * 32 + i) * 2048 + h * 64 + d0) = ov;
}

// ---------------- launch ----------------

extern "C" void kernel_launch(void* const* d_in, const int* in_sizes, int n_in,
                              void* d_out, int out_size, void* d_ws, size_t ws_size,
                              hipStream_t stream) {
  const float* x   = (const float*)d_in[0];
  const float* wq  = (const float*)d_in[1];
  const float* bq  = (const float*)d_in[2];
  const float* wk  = (const float*)d_in[3];
  const float* bk  = (const float*)d_in[4];
  const float* wv  = (const float*)d_in[5];
  const float* bv  = (const float*)d_in[6];
  const float* wo  = (const float*)d_in[7];
  const float* bo  = (const float*)d_in[8];
  const float* rpe = (const float*)d_in[9];

  char* ws = (char*)d_ws;
  unsigned short* xb    = (unsigned short*)(ws);
  unsigned short* wqkvb = (unsigned short*)(ws + 67108864);
  unsigned short* wob   = (unsigned short*)(ws + 67108864 + 25165824);
  unsigned short* qkvb  = (unsigned short*)(ws + 67108864 + 25165824 + 8388608);
  float*          bqkv  = (float*)(ws + 67108864 + 25165824 + 8388608 + 201326592);
  unsigned short* relb  = (unsigned short*)(ws + 67108864 + 25165824 + 8388608 + 201326592 + 24576);

  k_cast_f32_bf16<<<32768, 256, 0, stream>>>(x, xb, 8388608);          // 16384*2048/4
  k_build_wqkv<<<12288, 256, 0, stream>>>(wq, wk, wv, wqkvb);
  k_cast_f32_bf16<<<4096, 256, 0, stream>>>(wo, wob, 1048576);         // 2048*2048/4
  k_build_bqkv<<<24, 256, 0, stream>>>(bq, bk, bv, bqkv);
  k_build_rel<<<64, 256, 0, stream>>>(rpe, relb);

  // QKV projection: [16384][6144] = xb * wqkvb^T + bqkv  (bf16 out); grid 64x24=1536 (%8==0)
  k_gemm256<0><<<(16384 / 256) * (6144 / 256), 512, 0, stream>>>(
      xb, wqkvb, bqkv, qkvb, 16384, 6144, 2048);

  // attention -> ctx (reuses xb buffer)
  k_attn<<<16384, 256, 0, stream>>>(qkvb, relb, xb);

  // output projection: [16384][2048] = ctx * wob^T + bo  (fp32 out); grid 64x8=512 (%8==0)
  k_gemm256<1><<<(16384 / 256) * (2048 / 256), 512, 0, stream>>>(
      xb, wob, bo, (float*)d_out, 16384, 2048, 2048);
}

// Round 3
// 999.675 us; speedup vs baseline: 1.0505x; 1.0505x over previous
//
#include <hip/hip_runtime.h>
#include <hip/hip_bf16.h>
#include <stdint.h>

// B=512 L=32 E=2048 H=32 D=64 ; M = B*L = 16384 ; K = 2048 ; Nqkv = 6144
typedef __bf16 bf16x8 __attribute__((ext_vector_type(8)));
typedef float f32x4 __attribute__((ext_vector_type(4)));
typedef unsigned short u16x8 __attribute__((ext_vector_type(8)));
typedef unsigned short u16x4 __attribute__((ext_vector_type(4)));

#define G_AS __attribute__((address_space(1)))
#define L_AS __attribute__((address_space(3)))

__device__ __forceinline__ void gload_lds16(const void* g, void* l) {
  __builtin_amdgcn_global_load_lds((G_AS void*)g, (L_AS void*)l, 16, 0, 0);
}

__device__ __forceinline__ float b2f(unsigned short u) {
  union { float f; unsigned int i; } cv;
  cv.i = ((unsigned int)u) << 16;
  return cv.f;
}

__device__ __forceinline__ unsigned short f2b(float f) {
  unsigned int u = __float_as_uint(f);
  unsigned int r = u + 0x7FFFu + ((u >> 16) & 1u);  // RNE (inputs are non-NaN)
  return (unsigned short)(r >> 16);
}

// ---------------- cast / pack kernels ----------------

__global__ void k_cast_f32_bf16(const float* __restrict__ src,
                                unsigned short* __restrict__ dst, int n4) {
  int i = blockIdx.x * blockDim.x + threadIdx.x;
  if (i >= n4) return;
  float4 v = reinterpret_cast<const float4*>(src)[i];
  u16x4 o;
  o[0] = f2b(v.x); o[1] = f2b(v.y); o[2] = f2b(v.z); o[3] = f2b(v.w);
  reinterpret_cast<u16x4*>(dst)[i] = o;
}

// wqkvb rows: [0,2048)=wq, [2048,4096)=wk*0.125 (folds softmax scale), [4096,6144)=wv
__global__ void k_build_wqkv(const float* __restrict__ wq, const float* __restrict__ wk,
                             const float* __restrict__ wv, unsigned short* __restrict__ dst) {
  int i = blockIdx.x * blockDim.x + threadIdx.x;  // 6144*2048/4 = 3145728 threads
  if (i >= 3145728) return;
  int e = i << 2;
  int row = e >> 11;
  int col = e & 2047;
  const float* src; float sc = 1.0f;
  if (row < 2048) { src = wq + ((size_t)row << 11); }
  else if (row < 4096) { src = wk + ((size_t)(row - 2048) << 11); sc = 0.125f; }
  else { src = wv + ((size_t)(row - 4096) << 11); }
  float4 v = *reinterpret_cast<const float4*>(src + col);
  u16x4 o;
  o[0] = f2b(v.x * sc); o[1] = f2b(v.y * sc); o[2] = f2b(v.z * sc); o[3] = f2b(v.w * sc);
  *reinterpret_cast<u16x4*>(dst + e) = o;
}

__global__ void k_build_bqkv(const float* __restrict__ bq, const float* __restrict__ bk,
                             const float* __restrict__ bv, float* __restrict__ dst) {
  int i = blockIdx.x * blockDim.x + threadIdx.x;
  if (i >= 6144) return;
  float v;
  if (i < 2048) v = bq[i];
  else if (i < 4096) v = bk[i - 2048] * 0.125f;
  else v = bv[i - 4096];
  dst[i] = v;
}

// relb[h][j][d] = rpe[h - j + 31][d]   (faithful to the reference's H==L broadcast quirk)
__global__ void k_build_rel(const float* __restrict__ rpe, unsigned short* __restrict__ dst) {
  int i = blockIdx.x * blockDim.x + threadIdx.x;  // 32*32*16 = 16384
  if (i >= 16384) return;
  int h = i >> 9;
  int j = (i >> 4) & 31;
  int d = (i & 15) << 2;
  const float* s = rpe + (size_t)(h - j + 31) * 64 + d;
  float4 v = *reinterpret_cast<const float4*>(s);
  u16x4 o;
  o[0] = f2b(v.x); o[1] = f2b(v.y); o[2] = f2b(v.z); o[3] = f2b(v.w);
  *reinterpret_cast<u16x4*>(dst + ((size_t)i << 2)) = o;
}

// ---------------- GEMM: C[M][N] = A[M][K] * B[N][K]^T + bias[N] ----------------
// 256x256 tile, 8 waves (2Mx4N), 512 threads. BK=32, 4-buffer LDS ring (128 KiB),
// 2 fine phases per K-tile (16 MFMA + 2 gload_lds + 4/8 ds_reads + 2 barriers each),
// counted vmcnt(10) once per K-tile (never 0 until the 3-tile tail), setprio around
// MFMA clusters, bm-major bijective XCD swizzle.
//
// LDS chunk layout per (buf, matrix): 16B chunk for (row, slot) at
//   phys = (row>>3)*32 + slot*8 + (row&7)     slot = k/8 (0..3), rows 0..255
// -> a wave's ds_read_b128 (16 lanes x consecutive rows, 4 slot-groups) covers all
// 32 banks exactly 2x = conflict-free (verified 0 conflicts in round 2).
// Staging: linear dest chunk c = tid (+512); source row/col permuted to match:
//   row = ((c>>5)<<3)|(c&7), col8 = (c>>3)&3   (inverse verified: phys(row,slot)=c)

template <int OUT_F32>
__global__ __launch_bounds__(512, 2)
void k_gemm256(const unsigned short* __restrict__ A,
               const unsigned short* __restrict__ B,
               const float* __restrict__ bias,
               void* __restrict__ Cptr,
               int M, int N, int K)
{
  __shared__ __align__(16) unsigned short As[4][8192];
  __shared__ __align__(16) unsigned short Bs[4][8192];

  // bijective XCD swizzle, bm-major (consecutive logical wg share the A row-panel;
  // B is small (8-25 MB) and L3-resident -> low HBM fetch)
  const int nbn = N >> 8;
  const int cpx = gridDim.x >> 3;
  const int orig = blockIdx.x;
  const int wg = (orig & 7) * cpx + (orig >> 3);
  const int bm = wg / nbn;
  const int bn = wg % nbn;

  const int tid = threadIdx.x;
  const int lane = tid & 63;
  const int wid = tid >> 6;
  const int wr = wid >> 2;   // 0..1  (m-half of the 256 rows)
  const int wc = wid & 3;    // 0..3  (64-col strip)

  // ---- staging addresses (chunk c=tid covers rows 0..127, c+512 rows 128..255) ----
  const int rs = ((tid >> 5) << 3) + (tid & 7);
  const int cs = ((tid >> 3) & 3) << 3;
  const unsigned short* agA0 = A + (size_t)(bm * 256 + rs) * K + cs;
  const unsigned short* agA1 = agA0 + (size_t)128 * K;
  const unsigned short* agB0 = B + (size_t)(bn * 256 + rs) * K + cs;
  const unsigned short* agB1 = agB0 + (size_t)128 * K;
  const int ldst = tid * 8;   // ushort index of chunk tid; +4096 for chunk tid+512

  // ---- fragment read offsets (ushort index inside one 8192-ushort matrix-buf) ----
  const int fr = lane & 15;
  const int q  = lane >> 4;                     // k-slot 0..3
  const int rbase = (fr >> 3) * 256 + q * 64 + (fr & 7) * 8;
  const int aOff = wr * 4096 + rbase;           // + m*512, m=0..7
  const int bOff = wc * 2048 + rbase;           // + n*512, n=0..3

  f32x4 acc[8][4] = {};
  const int NT = K >> 5;   // 64 K-tiles

  // prologue: stage tiles 0..2 into bufs 0..2 (order per tile: A,A,B,B)
#pragma unroll
  for (int pf = 0; pf < 3; ++pf) {
    const int kof = pf << 5;
    gload_lds16(agA0 + kof, &As[pf][ldst]);
    gload_lds16(agA1 + kof, &As[pf][ldst + 4096]);
    gload_lds16(agB0 + kof, &Bs[pf][ldst]);
    gload_lds16(agB1 + kof, &Bs[pf][ldst + 4096]);
  }

  for (int t = 0; t < NT; ++t) {
    const unsigned short* ab = &As[t & 3][0];
    const unsigned short* bb = &Bs[t & 3][0];
    const int stg = t + 3;
    const bool st = stg < NT;                  // uniform
    unsigned short* dA = &As[stg & 3][ldst];
    unsigned short* dB = &Bs[stg & 3][ldst];
    const int kof = stg << 5;

    // ================= phase 0 =================
    if (st) {
      gload_lds16(agA0 + kof, dA);
      gload_lds16(agA1 + kof, dA + 4096);
    }
    // wait for tile t's 4 loads; keep tiles t+1,t+2 (+ own 2 A-loads) in flight
    if (st)              asm volatile("s_waitcnt vmcnt(10)" ::: "memory");
    else if (t + 2 < NT) asm volatile("s_waitcnt vmcnt(8)"  ::: "memory");
    else if (t + 1 < NT) asm volatile("s_waitcnt vmcnt(4)"  ::: "memory");
    else                 asm volatile("s_waitcnt vmcnt(0)"  ::: "memory");
    asm volatile("s_barrier" ::: "memory");     // all waves' tile-t DMA landed

    bf16x8 af[4], bfv[4];
#pragma unroll
    for (int n = 0; n < 4; ++n)
      bfv[n] = *reinterpret_cast<const bf16x8*>(bb + bOff + n * 512);
#pragma unroll
    for (int m = 0; m < 4; ++m)
      af[m] = *reinterpret_cast<const bf16x8*>(ab + aOff + m * 512);
    __builtin_amdgcn_s_setprio(1);
#pragma unroll
    for (int m = 0; m < 4; ++m)
#pragma unroll
      for (int n = 0; n < 4; ++n)
        acc[m][n] = __builtin_amdgcn_mfma_f32_16x16x32_bf16(af[m], bfv[n], acc[m][n], 0, 0, 0);
    __builtin_amdgcn_s_setprio(0);
    asm volatile("s_barrier" ::: "memory");

    // ================= phase 1 =================
    bf16x8 af2[4];
#pragma unroll
    for (int m = 0; m < 4; ++m)
      af2[m] = *reinterpret_cast<const bf16x8*>(ab + aOff + (4 + m) * 512);
    if (st) {
      gload_lds16(agB0 + kof, dB);
      gload_lds16(agB1 + kof, dB + 4096);
    }
    asm volatile("s_barrier" ::: "memory");
    __builtin_amdgcn_s_setprio(1);
#pragma unroll
    for (int m = 0; m < 4; ++m)
#pragma unroll
      for (int n = 0; n < 4; ++n)
        acc[4 + m][n] = __builtin_amdgcn_mfma_f32_16x16x32_bf16(af2[m], bfv[n], acc[4 + m][n], 0, 0, 0);
    __builtin_amdgcn_s_setprio(0);
    asm volatile("s_barrier" ::: "memory");     // buf (t&3) reads done -> may overwrite
  }

  // epilogue: C/D layout col = lane&15, row = (lane>>4)*4 + reg
  const int rBase = bm * 256 + wr * 128 + (q << 2);
  const int cBase = bn * 256 + wc * 64 + fr;
#pragma unroll
  for (int n = 0; n < 4; ++n) {
    const int col = cBase + n * 16;
    const float bv = bias[col];
#pragma unroll
    for (int m = 0; m < 8; ++m) {
      const int row = rBase + m * 16;
#pragma unroll
      for (int r = 0; r < 4; ++r) {
        float v = acc[m][n][r] + bv;
        if (OUT_F32) {
          reinterpret_cast<float*>(Cptr)[(size_t)(row + r) * N + col] = v;
        } else {
          reinterpret_cast<unsigned short*>(Cptr)[(size_t)(row + r) * N + col] = f2b(v);
        }
      }
    }
  }
}

// ---------------- attention: one block (256 thr) per (b,h) ----------------
// qkv row-major [16384][6144]; q at col h*64, k(prescaled) at 2048+h*64, v at 4096+h*64
// S[i][j] = sum_d q[i,d]*(k_s[j,d] + rel[h,j,d]) ; softmax over j ; ctx = P·V

__global__ __launch_bounds__(256)
void k_attn(const unsigned short* __restrict__ qkv,
            const unsigned short* __restrict__ relb,
            unsigned short* __restrict__ ctx)
{
  __shared__ float qL[32][68];
  __shared__ float krL[32][68];
  __shared__ float vL[32][68];
  __shared__ float SL[32][33];

  const int bh = blockIdx.x;
  const int b = bh >> 5;
  const int h = bh & 31;
  const int t = threadIdx.x;
  const int r = t >> 3;           // row 0..31
  const int d0 = (t & 7) << 3;    // d 0..56 step 8

  const unsigned short* base = qkv + (size_t)(b * 32 + r) * 6144 + h * 64 + d0;
  u16x8 uq = *reinterpret_cast<const u16x8*>(base);
  u16x8 uk = *reinterpret_cast<const u16x8*>(base + 2048);
  u16x8 uv = *reinterpret_cast<const u16x8*>(base + 4096);
  u16x8 ur = *reinterpret_cast<const u16x8*>(relb + (((size_t)(h * 32 + r)) << 6) + d0);

  float fq[8], fkr[8], fv[8];
#pragma unroll
  for (int c = 0; c < 8; ++c) {
    fq[c] = b2f(uq[c]);
    fkr[c] = b2f(uk[c]) + b2f(ur[c]);
    fv[c] = b2f(uv[c]);
  }
  *reinterpret_cast<float4*>(&qL[r][d0])      = make_float4(fq[0], fq[1], fq[2], fq[3]);
  *reinterpret_cast<float4*>(&qL[r][d0 + 4])  = make_float4(fq[4], fq[5], fq[6], fq[7]);
  *reinterpret_cast<float4*>(&krL[r][d0])     = make_float4(fkr[0], fkr[1], fkr[2], fkr[3]);
  *reinterpret_cast<float4*>(&krL[r][d0 + 4]) = make_float4(fkr[4], fkr[5], fkr[6], fkr[7]);
  *reinterpret_cast<float4*>(&vL[r][d0])      = make_float4(fv[0], fv[1], fv[2], fv[3]);
  *reinterpret_cast<float4*>(&vL[r][d0 + 4])  = make_float4(fv[4], fv[5], fv[6], fv[7]);
  __syncthreads();

  const int i = r;
  const int j0 = (t & 7) << 2;   // 4 score cols per thread
  float s0 = 0.f, s1 = 0.f, s2 = 0.f, s3 = 0.f;
#pragma unroll
  for (int d = 0; d < 64; d += 4) {
    float4 qv = *reinterpret_cast<const float4*>(&qL[i][d]);
    float4 k0 = *reinterpret_cast<const float4*>(&krL[j0 + 0][d]);
    float4 k1 = *reinterpret_cast<const float4*>(&krL[j0 + 1][d]);
    float4 k2 = *reinterpret_cast<const float4*>(&krL[j0 + 2][d]);
    float4 k3 = *reinterpret_cast<const float4*>(&krL[j0 + 3][d]);
    s0 += qv.x * k0.x + qv.y * k0.y + qv.z * k0.z + qv.w * k0.w;
    s1 += qv.x * k1.x + qv.y * k1.y + qv.z * k1.z + qv.w * k1.w;
    s2 += qv.x * k2.x + qv.y * k2.y + qv.z * k2.z + qv.w * k2.w;
    s3 += qv.x * k3.x + qv.y * k3.y + qv.z * k3.z + qv.w * k3.w;
  }
  SL[i][j0 + 0] = s0; SL[i][j0 + 1] = s1; SL[i][j0 + 2] = s2; SL[i][j0 + 3] = s3;
  __syncthreads();

  float m = SL[i][0];
#pragma unroll
  for (int jj = 1; jj < 32; ++jj) m = fmaxf(m, SL[i][jj]);
  __syncthreads();  // all max reads done before P overwrites S

  float p0 = __expf(s0 - m), p1 = __expf(s1 - m), p2 = __expf(s2 - m), p3 = __expf(s3 - m);
  SL[i][j0 + 0] = p0; SL[i][j0 + 1] = p1; SL[i][j0 + 2] = p2; SL[i][j0 + 3] = p3;
  __syncthreads();

  float den = 0.f;
#pragma unroll
  for (int jj = 0; jj < 32; ++jj) den += SL[i][jj];
  const float inv = 1.0f / den;

  float o[8] = {0.f, 0.f, 0.f, 0.f, 0.f, 0.f, 0.f, 0.f};
#pragma unroll
  for (int jj = 0; jj < 32; ++jj) {
    float pj = SL[i][jj];
    float4 v0 = *reinterpret_cast<const float4*>(&vL[jj][d0]);
    float4 v1 = *reinterpret_cast<const float4*>(&vL[jj][d0 + 4]);
    o[0] += pj * v0.x; o[1] += pj * v0.y; o[2] += pj * v0.z; o[3] += pj * v0.w;
    o[4] += pj * v1.x; o[5] += pj * v1.y; o[6] += pj * v1.z; o[7] += pj * v1.w;
  }
  u16x8 ov;
#pragma unroll
  for (int c = 0; c < 8; ++c) ov[c] = f2b(o[c] * inv);
  *reinterpret_cast<u16x8*>(ctx + (size_t)(b * 32 + i) * 2048 + h * 64 + d0) = ov;
}

// ---------------- launch ----------------

extern "C" void kernel_launch(void* const* d_in, const int* in_sizes, int n_in,
                              void* d_out, int out_size, void* d_ws, size_t ws_size,
                              hipStream_t stream) {
  const float* x   = (const float*)d_in[0];
  const float* wq  = (const float*)d_in[1];
  const float* bq  = (const float*)d_in[2];
  const float* wk  = (const float*)d_in[3];
  const float* bk  = (const float*)d_in[4];
  const float* wv  = (const float*)d_in[5];
  const float* bv  = (const float*)d_in[6];
  const float* wo  = (const float*)d_in[7];
  const float* bo  = (const float*)d_in[8];
  const float* rpe = (const float*)d_in[9];

  char* ws = (char*)d_ws;
  unsigned short* xb    = (unsigned short*)(ws);
  unsigned short* wqkvb = (unsigned short*)(ws + 67108864);
  unsigned short* wob   = (unsigned short*)(ws + 67108864 + 25165824);
  unsigned short* qkvb  = (unsigned short*)(ws + 67108864 + 25165824 + 8388608);
  float*          bqkv  = (float*)(ws + 67108864 + 25165824 + 8388608 + 201326592);
  unsigned short* relb  = (unsigned short*)(ws + 67108864 + 25165824 + 8388608 + 201326592 + 24576);

  k_cast_f32_bf16<<<32768, 256, 0, stream>>>(x, xb, 8388608);          // 16384*2048/4
  k_build_wqkv<<<12288, 256, 0, stream>>>(wq, wk, wv, wqkvb);
  k_cast_f32_bf16<<<4096, 256, 0, stream>>>(wo, wob, 1048576);         // 2048*2048/4
  k_build_bqkv<<<24, 256, 0, stream>>>(bq, bk, bv, bqkv);
  k_build_rel<<<64, 256, 0, stream>>>(rpe, relb);

  // QKV projection: [16384][6144] = xb * wqkvb^T + bqkv  (bf16 out); grid 64x24=1536 (%8==0)
  k_gemm256<0><<<(16384 / 256) * (6144 / 256), 512, 0, stream>>>(
      xb, wqkvb, bqkv, qkvb, 16384, 6144, 2048);

  // attention -> ctx (reuses xb buffer)
  k_attn<<<16384, 256, 0, stream>>>(qkvb, relb, xb);

  // output projection: [16384][2048] = ctx * wob^T + bo  (fp32 out); grid 64x8=512 (%8==0)
  k_gemm256<1><<<(16384 / 256) * (2048 / 256), 512, 0, stream>>>(
      xb, wob, bo, (float*)d_out, 16384, 2048, 2048);
}

// Round 4
// 984.354 us; speedup vs baseline: 1.0669x; 1.0156x over previous
//
#include <hip/hip_runtime.h>
#include <hip/hip_bf16.h>
#include <stdint.h>

// B=512 L=32 E=2048 H=32 D=64 ; M = B*L = 16384 ; K = 2048 ; Nqkv = 6144
typedef __bf16 bf16x8 __attribute__((ext_vector_type(8)));
typedef float f32x4 __attribute__((ext_vector_type(4)));
typedef unsigned short u16x8 __attribute__((ext_vector_type(8)));
typedef unsigned short u16x4 __attribute__((ext_vector_type(4)));

#define G_AS __attribute__((address_space(1)))
#define L_AS __attribute__((address_space(3)))

__device__ __forceinline__ void gload_lds16(const void* g, void* l) {
  __builtin_amdgcn_global_load_lds((G_AS void*)g, (L_AS void*)l, 16, 0, 0);
}

__device__ __forceinline__ float b2f(unsigned short u) {
  union { float f; unsigned int i; } cv;
  cv.i = ((unsigned int)u) << 16;
  return cv.f;
}

__device__ __forceinline__ unsigned short f2b(float f) {
  unsigned int u = __float_as_uint(f);
  unsigned int r = u + 0x7FFFu + ((u >> 16) & 1u);  // RNE (inputs are non-NaN)
  return (unsigned short)(r >> 16);
}

// ---------------- cast / pack kernels ----------------

__global__ void k_cast_f32_bf16(const float* __restrict__ src,
                                unsigned short* __restrict__ dst, int n4) {
  int i = blockIdx.x * blockDim.x + threadIdx.x;
  if (i >= n4) return;
  float4 v = reinterpret_cast<const float4*>(src)[i];
  u16x4 o;
  o[0] = f2b(v.x); o[1] = f2b(v.y); o[2] = f2b(v.z); o[3] = f2b(v.w);
  reinterpret_cast<u16x4*>(dst)[i] = o;
}

// wqkvb rows: [0,2048)=wq, [2048,4096)=wk*0.125 (folds softmax scale), [4096,6144)=wv
__global__ void k_build_wqkv(const float* __restrict__ wq, const float* __restrict__ wk,
                             const float* __restrict__ wv, unsigned short* __restrict__ dst) {
  int i = blockIdx.x * blockDim.x + threadIdx.x;  // 6144*2048/4 = 3145728 threads
  if (i >= 3145728) return;
  int e = i << 2;
  int row = e >> 11;
  int col = e & 2047;
  const float* src; float sc = 1.0f;
  if (row < 2048) { src = wq + ((size_t)row << 11); }
  else if (row < 4096) { src = wk + ((size_t)(row - 2048) << 11); sc = 0.125f; }
  else { src = wv + ((size_t)(row - 4096) << 11); }
  float4 v = *reinterpret_cast<const float4*>(src + col);
  u16x4 o;
  o[0] = f2b(v.x * sc); o[1] = f2b(v.y * sc); o[2] = f2b(v.z * sc); o[3] = f2b(v.w * sc);
  *reinterpret_cast<u16x4*>(dst + e) = o;
}

__global__ void k_build_bqkv(const float* __restrict__ bq, const float* __restrict__ bk,
                             const float* __restrict__ bv, float* __restrict__ dst) {
  int i = blockIdx.x * blockDim.x + threadIdx.x;
  if (i >= 6144) return;
  float v;
  if (i < 2048) v = bq[i];
  else if (i < 4096) v = bk[i - 2048] * 0.125f;
  else v = bv[i - 4096];
  dst[i] = v;
}

// relb[h][j][d] = rpe[h - j + 31][d]   (faithful to the reference's H==L broadcast quirk)
__global__ void k_build_rel(const float* __restrict__ rpe, unsigned short* __restrict__ dst) {
  int i = blockIdx.x * blockDim.x + threadIdx.x;  // 32*32*16 = 16384
  if (i >= 16384) return;
  int h = i >> 9;
  int j = (i >> 4) & 31;
  int d = (i & 15) << 2;
  const float* s = rpe + (size_t)(h - j + 31) * 64 + d;
  float4 v = *reinterpret_cast<const float4*>(s);
  u16x4 o;
  o[0] = f2b(v.x); o[1] = f2b(v.y); o[2] = f2b(v.z); o[3] = f2b(v.w);
  *reinterpret_cast<u16x4*>(dst + ((size_t)i << 2)) = o;
}

// ---------------- GEMM: C[M][N] = A[M][K] * B[N][K]^T + bias[N] ----------------
// 256x256 tile, 8 waves (2Mx4N), 512 threads. BK=32, 4-buffer LDS ring (128 KiB).
// Software-pipelined register fragments: every ds_read is issued >=1 MFMA cluster
// before its consuming cluster, so LDS latency hides under MFMA. One counted
// vmcnt (8/4/0 only in the 2-tile tail) + 2 raw barriers per K-tile.
//
// LDS chunk layout per (buf, matrix): 16B chunk for (row, slot) at
//   phys = (row>>3)*32 + slot*8 + (row&7)   slot = k/8 (0..3)
// -> conflict-free ds_read_b128 (verified 0 conflicts in rounds 2-3).
// Staging: linear dest chunk = tid (+512); global source row/col permuted to match.
//
// Hazard ledger (4-buf ring, stage t+3 at iter t):
//  RAW: frags of buf (t+1) read at iter-t step5, after vmcnt(>= t+1 landed)+barrier. OK
//  WAR: DMA into buf b at iter t overwrites tile t-1; all reads of buf (t-1)
//       (af2 of iter t-1) are consumed by MFMA before iter t-1's end barrier. OK

template <int OUT_F32>
__global__ __launch_bounds__(512, 2)
void k_gemm256(const unsigned short* __restrict__ A,
               const unsigned short* __restrict__ B,
               const float* __restrict__ bias,
               void* __restrict__ Cptr,
               int M, int N, int K)
{
  __shared__ __align__(16) unsigned short As[4][8192];
  __shared__ __align__(16) unsigned short Bs[4][8192];

  // bijective XCD swizzle, bm-major
  const int nbn = N >> 8;
  const int cpx = gridDim.x >> 3;
  const int orig = blockIdx.x;
  const int wg = (orig & 7) * cpx + (orig >> 3);
  const int bm = wg / nbn;
  const int bn = wg % nbn;

  const int tid = threadIdx.x;
  const int lane = tid & 63;
  const int wid = tid >> 6;
  const int wr = wid >> 2;   // 0..1  (m-half)
  const int wc = wid & 3;    // 0..3  (64-col strip)

  // staging addresses (chunk c=tid covers rows 0..127, c+512 rows 128..255)
  const int rs = ((tid >> 5) << 3) + (tid & 7);
  const int cs = ((tid >> 3) & 3) << 3;
  const unsigned short* agA0 = A + (size_t)(bm * 256 + rs) * K + cs;
  const unsigned short* agA1 = agA0 + (size_t)128 * K;
  const unsigned short* agB0 = B + (size_t)(bn * 256 + rs) * K + cs;
  const unsigned short* agB1 = agB0 + (size_t)128 * K;
  const int ldst = tid * 8;

  // fragment read offsets (ushort index inside one 8192-ushort matrix-buf)
  const int fr = lane & 15;
  const int q  = lane >> 4;                     // k-slot 0..3
  const int rbase = (fr >> 3) * 256 + q * 64 + (fr & 7) * 8;
  const int aOff = wr * 4096 + rbase;           // + m*512, m=0..7
  const int bOff = wc * 2048 + rbase;           // + n*512, n=0..3

  f32x4 acc[8][4] = {};
  bf16x8 afA[4], af2[4], bfv[4], afn[4], bfvn[4];
  const int NT = K >> 5;   // 64 K-tiles

  // prologue: stage tiles 0..2
#pragma unroll
  for (int pf = 0; pf < 3; ++pf) {
    const int kof = pf << 5;
    gload_lds16(agA0 + kof, &As[pf][ldst]);
    gload_lds16(agA1 + kof, &As[pf][ldst + 4096]);
    gload_lds16(agB0 + kof, &Bs[pf][ldst]);
    gload_lds16(agB1 + kof, &Bs[pf][ldst + 4096]);
  }
  asm volatile("s_waitcnt vmcnt(8)" ::: "memory");   // tile 0 landed (all waves below)
  asm volatile("s_barrier" ::: "memory");
#pragma unroll
  for (int n = 0; n < 4; ++n)
    bfv[n] = *reinterpret_cast<const bf16x8*>(&Bs[0][0] + bOff + n * 512);
#pragma unroll
  for (int m = 0; m < 4; ++m)
    afA[m] = *reinterpret_cast<const bf16x8*>(&As[0][0] + aOff + m * 512);

  for (int t = 0; t < NT; ++t) {
    const unsigned short* ab = &As[t & 3][0];
    // cluster-B frags for THIS tile (buf valid since previous tile's wait)
#pragma unroll
    for (int m = 0; m < 4; ++m)
      af2[m] = *reinterpret_cast<const bf16x8*>(ab + aOff + (4 + m) * 512);

    const int stg = t + 3;
    if (stg < NT) {
      unsigned short* dA = &As[stg & 3][ldst];
      unsigned short* dB = &Bs[stg & 3][ldst];
      const int kof = stg << 5;
      gload_lds16(agA0 + kof, dA);
      gload_lds16(agA1 + kof, dA + 4096);
      gload_lds16(agB0 + kof, dB);
      gload_lds16(agB1 + kof, dB + 4096);
    }
    const int rem = NT - 1 - t;
    if (rem > 0) {
      // guarantee tile t+1 landed (for the next-tile frag prefetch below)
      if (rem >= 3)      asm volatile("s_waitcnt vmcnt(8)" ::: "memory");
      else if (rem == 2) asm volatile("s_waitcnt vmcnt(4)" ::: "memory");
      else               asm volatile("s_waitcnt vmcnt(0)" ::: "memory");
      asm volatile("s_barrier" ::: "memory");
    }

    // cluster A: frags prefetched during previous iteration
    __builtin_amdgcn_s_setprio(1);
#pragma unroll
    for (int m = 0; m < 4; ++m)
#pragma unroll
      for (int n = 0; n < 4; ++n)
        acc[m][n] = __builtin_amdgcn_mfma_f32_16x16x32_bf16(afA[m], bfv[n], acc[m][n], 0, 0, 0);
    __builtin_amdgcn_s_setprio(0);

    // prefetch next tile's cluster-A frags (hidden under cluster B)
    if (rem > 0) {
      const unsigned short* abn = &As[(t + 1) & 3][0];
      const unsigned short* bbn = &Bs[(t + 1) & 3][0];
#pragma unroll
      for (int n = 0; n < 4; ++n)
        bfvn[n] = *reinterpret_cast<const bf16x8*>(bbn + bOff + n * 512);
#pragma unroll
      for (int m = 0; m < 4; ++m)
        afn[m] = *reinterpret_cast<const bf16x8*>(abn + aOff + m * 512);
    }

    // cluster B: af2 issued at loop top (latency long since covered)
    __builtin_amdgcn_s_setprio(1);
#pragma unroll
    for (int m = 0; m < 4; ++m)
#pragma unroll
      for (int n = 0; n < 4; ++n)
        acc[4 + m][n] = __builtin_amdgcn_mfma_f32_16x16x32_bf16(af2[m], bfv[n], acc[4 + m][n], 0, 0, 0);
    __builtin_amdgcn_s_setprio(0);
    asm volatile("s_barrier" ::: "memory");   // all reads of buf (t&3) done

    if (rem > 0) {
#pragma unroll
      for (int m = 0; m < 4; ++m) afA[m] = afn[m];
#pragma unroll
      for (int n = 0; n < 4; ++n) bfv[n] = bfvn[n];
    }
  }

  // epilogue: C/D layout col = lane&15, row = (lane>>4)*4 + reg
  const int rBase = bm * 256 + wr * 128 + (q << 2);
  const int cBase = bn * 256 + wc * 64 + fr;
#pragma unroll
  for (int n = 0; n < 4; ++n) {
    const int col = cBase + n * 16;
    const float bv = bias[col];
#pragma unroll
    for (int m = 0; m < 8; ++m) {
      const int row = rBase + m * 16;
#pragma unroll
      for (int r = 0; r < 4; ++r) {
        float v = acc[m][n][r] + bv;
        if (OUT_F32) {
          reinterpret_cast<float*>(Cptr)[(size_t)(row + r) * N + col] = v;
        } else {
          reinterpret_cast<unsigned short*>(Cptr)[(size_t)(row + r) * N + col] = f2b(v);
        }
      }
    }
  }
}

// ---------------- attention: one block (256 thr) per (b,h) ----------------

__global__ __launch_bounds__(256)
void k_attn(const unsigned short* __restrict__ qkv,
            const unsigned short* __restrict__ relb,
            unsigned short* __restrict__ ctx)
{
  __shared__ float qL[32][68];
  __shared__ float krL[32][68];
  __shared__ float vL[32][68];
  __shared__ float SL[32][33];

  const int bh = blockIdx.x;
  const int b = bh >> 5;
  const int h = bh & 31;
  const int t = threadIdx.x;
  const int r = t >> 3;           // row 0..31
  const int d0 = (t & 7) << 3;    // d 0..56 step 8

  const unsigned short* base = qkv + (size_t)(b * 32 + r) * 6144 + h * 64 + d0;
  u16x8 uq = *reinterpret_cast<const u16x8*>(base);
  u16x8 uk = *reinterpret_cast<const u16x8*>(base + 2048);
  u16x8 uv = *reinterpret_cast<const u16x8*>(base + 4096);
  u16x8 ur = *reinterpret_cast<const u16x8*>(relb + (((size_t)(h * 32 + r)) << 6) + d0);

  float fq[8], fkr[8], fv[8];
#pragma unroll
  for (int c = 0; c < 8; ++c) {
    fq[c] = b2f(uq[c]);
    fkr[c] = b2f(uk[c]) + b2f(ur[c]);
    fv[c] = b2f(uv[c]);
  }
  *reinterpret_cast<float4*>(&qL[r][d0])      = make_float4(fq[0], fq[1], fq[2], fq[3]);
  *reinterpret_cast<float4*>(&qL[r][d0 + 4])  = make_float4(fq[4], fq[5], fq[6], fq[7]);
  *reinterpret_cast<float4*>(&krL[r][d0])     = make_float4(fkr[0], fkr[1], fkr[2], fkr[3]);
  *reinterpret_cast<float4*>(&krL[r][d0 + 4]) = make_float4(fkr[4], fkr[5], fkr[6], fkr[7]);
  *reinterpret_cast<float4*>(&vL[r][d0])      = make_float4(fv[0], fv[1], fv[2], fv[3]);
  *reinterpret_cast<float4*>(&vL[r][d0 + 4])  = make_float4(fv[4], fv[5], fv[6], fv[7]);
  __syncthreads();

  const int i = r;
  const int j0 = (t & 7) << 2;   // 4 score cols per thread
  float s0 = 0.f, s1 = 0.f, s2 = 0.f, s3 = 0.f;
#pragma unroll
  for (int d = 0; d < 64; d += 4) {
    float4 qv = *reinterpret_cast<const float4*>(&qL[i][d]);
    float4 k0 = *reinterpret_cast<const float4*>(&krL[j0 + 0][d]);
    float4 k1 = *reinterpret_cast<const float4*>(&krL[j0 + 1][d]);
    float4 k2 = *reinterpret_cast<const float4*>(&krL[j0 + 2][d]);
    float4 k3 = *reinterpret_cast<const float4*>(&krL[j0 + 3][d]);
    s0 += qv.x * k0.x + qv.y * k0.y + qv.z * k0.z + qv.w * k0.w;
    s1 += qv.x * k1.x + qv.y * k1.y + qv.z * k1.z + qv.w * k1.w;
    s2 += qv.x * k2.x + qv.y * k2.y + qv.z * k2.z + qv.w * k2.w;
    s3 += qv.x * k3.x + qv.y * k3.y + qv.z * k3.z + qv.w * k3.w;
  }
  SL[i][j0 + 0] = s0; SL[i][j0 + 1] = s1; SL[i][j0 + 2] = s2; SL[i][j0 + 3] = s3;
  __syncthreads();

  float m = SL[i][0];
#pragma unroll
  for (int jj = 1; jj < 32; ++jj) m = fmaxf(m, SL[i][jj]);
  __syncthreads();  // all max reads done before P overwrites S

  float p0 = __expf(s0 - m), p1 = __expf(s1 - m), p2 = __expf(s2 - m), p3 = __expf(s3 - m);
  SL[i][j0 + 0] = p0; SL[i][j0 + 1] = p1; SL[i][j0 + 2] = p2; SL[i][j0 + 3] = p3;
  __syncthreads();

  float den = 0.f;
#pragma unroll
  for (int jj = 0; jj < 32; ++jj) den += SL[i][jj];
  const float inv = 1.0f / den;

  float o[8] = {0.f, 0.f, 0.f, 0.f, 0.f, 0.f, 0.f, 0.f};
#pragma unroll
  for (int jj = 0; jj < 32; ++jj) {
    float pj = SL[i][jj];
    float4 v0 = *reinterpret_cast<const float4*>(&vL[jj][d0]);
    float4 v1 = *reinterpret_cast<const float4*>(&vL[jj][d0 + 4]);
    o[0] += pj * v0.x; o[1] += pj * v0.y; o[2] += pj * v0.z; o[3] += pj * v0.w;
    o[4] += pj * v1.x; o[5] += pj * v1.y; o[6] += pj * v1.z; o[7] += pj * v1.w;
  }
  u16x8 ov;
#pragma unroll
  for (int c = 0; c < 8; ++c) ov[c] = f2b(o[c] * inv);
  *reinterpret_cast<u16x8*>(ctx + (size_t)(b * 32 + i) * 2048 + h * 64 + d0) = ov;
}

// ---------------- launch ----------------

extern "C" void kernel_launch(void* const* d_in, const int* in_sizes, int n_in,
                              void* d_out, int out_size, void* d_ws, size_t ws_size,
                              hipStream_t stream) {
  const float* x   = (const float*)d_in[0];
  const float* wq  = (const float*)d_in[1];
  const float* bq  = (const float*)d_in[2];
  const float* wk  = (const float*)d_in[3];
  const float* bk  = (const float*)d_in[4];
  const float* wv  = (const float*)d_in[5];
  const float* bv  = (const float*)d_in[6];
  const float* wo  = (const float*)d_in[7];
  const float* bo  = (const float*)d_in[8];
  const float* rpe = (const float*)d_in[9];

  char* ws = (char*)d_ws;
  unsigned short* xb    = (unsigned short*)(ws);
  unsigned short* wqkvb = (unsigned short*)(ws + 67108864);
  unsigned short* wob   = (unsigned short*)(ws + 67108864 + 25165824);
  unsigned short* qkvb  = (unsigned short*)(ws + 67108864 + 25165824 + 8388608);
  float*          bqkv  = (float*)(ws + 67108864 + 25165824 + 8388608 + 201326592);
  unsigned short* relb  = (unsigned short*)(ws + 67108864 + 25165824 + 8388608 + 201326592 + 24576);

  k_cast_f32_bf16<<<32768, 256, 0, stream>>>(x, xb, 8388608);          // 16384*2048/4
  k_build_wqkv<<<12288, 256, 0, stream>>>(wq, wk, wv, wqkvb);
  k_cast_f32_bf16<<<4096, 256, 0, stream>>>(wo, wob, 1048576);         // 2048*2048/4
  k_build_bqkv<<<24, 256, 0, stream>>>(bq, bk, bv, bqkv);
  k_build_rel<<<64, 256, 0, stream>>>(rpe, relb);

  // QKV projection: [16384][6144] = xb * wqkvb^T + bqkv  (bf16 out); grid 64x24=1536 (%8==0)
  k_gemm256<0><<<(16384 / 256) * (6144 / 256), 512, 0, stream>>>(
      xb, wqkvb, bqkv, qkvb, 16384, 6144, 2048);

  // attention -> ctx (reuses xb buffer)
  k_attn<<<16384, 256, 0, stream>>>(qkvb, relb, xb);

  // output projection: [16384][2048] = ctx * wob^T + bo  (fp32 out); grid 64x8=512 (%8==0)
  k_gemm256<1><<<(16384 / 256) * (2048 / 256), 512, 0, stream>>>(
      xb, wob, bo, (float*)d_out, 16384, 2048, 2048);
}

// Round 5
// 856.692 us; speedup vs baseline: 1.2259x; 1.1490x over previous
//
#include <hip/hip_runtime.h>
#include <hip/hip_bf16.h>
#include <stdint.h>

// B=512 L=32 E=2048 H=32 D=64 ; M = B*L = 16384 ; K = 2048 ; Nqkv = 6144
typedef __bf16 bf16x8 __attribute__((ext_vector_type(8)));
typedef float f32x4 __attribute__((ext_vector_type(4)));
typedef unsigned short u16x8 __attribute__((ext_vector_type(8)));
typedef unsigned short u16x4 __attribute__((ext_vector_type(4)));

#define G_AS __attribute__((address_space(1)))
#define L_AS __attribute__((address_space(3)))

__device__ __forceinline__ void gload_lds16(const void* g, void* l) {
  __builtin_amdgcn_global_load_lds((G_AS void*)g, (L_AS void*)l, 16, 0, 0);
}

__device__ __forceinline__ float b2f(unsigned short u) {
  union { float f; unsigned int i; } cv;
  cv.i = ((unsigned int)u) << 16;
  return cv.f;
}

__device__ __forceinline__ unsigned short f2b(float f) {
  unsigned int u = __float_as_uint(f);
  unsigned int r = u + 0x7FFFu + ((u >> 16) & 1u);  // RNE (inputs are non-NaN)
  return (unsigned short)(r >> 16);
}

// ---------------- cast / pack kernels ----------------

__global__ void k_cast_f32_bf16(const float* __restrict__ src,
                                unsigned short* __restrict__ dst, int n4) {
  int i = blockIdx.x * blockDim.x + threadIdx.x;
  if (i >= n4) return;
  float4 v = reinterpret_cast<const float4*>(src)[i];
  u16x4 o;
  o[0] = f2b(v.x); o[1] = f2b(v.y); o[2] = f2b(v.z); o[3] = f2b(v.w);
  reinterpret_cast<u16x4*>(dst)[i] = o;
}

// wqkvb rows: [0,2048)=wq, [2048,4096)=wk*0.125 (folds softmax scale), [4096,6144)=wv
__global__ void k_build_wqkv(const float* __restrict__ wq, const float* __restrict__ wk,
                             const float* __restrict__ wv, unsigned short* __restrict__ dst) {
  int i = blockIdx.x * blockDim.x + threadIdx.x;  // 6144*2048/4 = 3145728 threads
  if (i >= 3145728) return;
  int e = i << 2;
  int row = e >> 11;
  int col = e & 2047;
  const float* src; float sc = 1.0f;
  if (row < 2048) { src = wq + ((size_t)row << 11); }
  else if (row < 4096) { src = wk + ((size_t)(row - 2048) << 11); sc = 0.125f; }
  else { src = wv + ((size_t)(row - 4096) << 11); }
  float4 v = *reinterpret_cast<const float4*>(src + col);
  u16x4 o;
  o[0] = f2b(v.x * sc); o[1] = f2b(v.y * sc); o[2] = f2b(v.z * sc); o[3] = f2b(v.w * sc);
  *reinterpret_cast<u16x4*>(dst + e) = o;
}

__global__ void k_build_bqkv(const float* __restrict__ bq, const float* __restrict__ bk,
                             const float* __restrict__ bv, float* __restrict__ dst) {
  int i = blockIdx.x * blockDim.x + threadIdx.x;
  if (i >= 6144) return;
  float v;
  if (i < 2048) v = bq[i];
  else if (i < 4096) v = bk[i - 2048] * 0.125f;
  else v = bv[i - 4096];
  dst[i] = v;
}

// relb[h][j][d] = rpe[h - j + 31][d]   (faithful to the reference's H==L broadcast quirk)
__global__ void k_build_rel(const float* __restrict__ rpe, unsigned short* __restrict__ dst) {
  int i = blockIdx.x * blockDim.x + threadIdx.x;  // 32*32*16 = 16384
  if (i >= 16384) return;
  int h = i >> 9;
  int j = (i >> 4) & 31;
  int d = (i & 15) << 2;
  const float* s = rpe + (size_t)(h - j + 31) * 64 + d;
  float4 v = *reinterpret_cast<const float4*>(s);
  u16x4 o;
  o[0] = f2b(v.x); o[1] = f2b(v.y); o[2] = f2b(v.z); o[3] = f2b(v.w);
  *reinterpret_cast<u16x4*>(dst + ((size_t)i << 2)) = o;
}

// ---------------- GEMM: C[M][N] = A[M][K] * B[N][K]^T + bias[N] ----------------
// 256x256 tile, 8 waves (2Mx4N), 512 threads. BK=32, 3-buffer LDS ring (96 KiB).
// FINE-PHASE schedule (m201-style): per K-tile 2 phases, each phase =
//   { 8-or-4 ds_read_b128  +  2 global_load_lds  (+ counted vmcnt once/tile) }
//   -> s_barrier -> setprio(1) 16 MFMA setprio(0) -> s_barrier
// vmcnt(4) per tile (tail: 4 -> 0), never a full drain in steady state.
//
// Wait ledger (per wave, at tile T phase-1 wait, steady state):
//   outstanding = tile T+1 (4 loads) + tile T+2 (4 loads just issued) = 8
//   vmcnt(4) -> completes T+1 exactly, leaves T+2 in flight.
// WAR: DMA into buf (T+2)%3 (= buf of T-1) issues after T-1.ph1's closing
//   barrier, which post-dates all T-1 reads (reads feed MFMA before barrier).
//
// LDS chunk layout per (buf, matrix): 16B chunk for (row, slot) at
//   phys = (row>>3)*32 + slot*8 + (row&7),  slot = k/8 (0..3)
// -> conflict-free ds_read_b128 (0 conflicts measured, rounds 2-4).
// Staging: linear dest chunk = tid (+512); global source row/col permuted.

template <int OUT_F32>
__global__ __launch_bounds__(512, 2)
void k_gemm256(const unsigned short* __restrict__ A,
               const unsigned short* __restrict__ B,
               const float* __restrict__ bias,
               void* __restrict__ Cptr,
               int M, int N, int K)
{
  __shared__ __align__(16) unsigned short As[3][8192];
  __shared__ __align__(16) unsigned short Bs[3][8192];

  // bijective XCD swizzle, bm-major
  const int nbn = N >> 8;
  const int cpx = gridDim.x >> 3;
  const int orig = blockIdx.x;
  const int wg = (orig & 7) * cpx + (orig >> 3);
  const int bm = wg / nbn;
  const int bn = wg % nbn;

  const int tid = threadIdx.x;
  const int lane = tid & 63;
  const int wid = tid >> 6;
  const int wr = wid >> 2;   // 0..1  (m-half)
  const int wc = wid & 3;    // 0..3  (64-col strip)

  // staging addresses (chunk c=tid covers rows 0..127, c+512 rows 128..255)
  const int rs = ((tid >> 5) << 3) + (tid & 7);
  const int cs = ((tid >> 3) & 3) << 3;
  const unsigned short* agA0 = A + (size_t)(bm * 256 + rs) * K + cs;
  const unsigned short* agA1 = agA0 + (size_t)128 * K;
  const unsigned short* agB0 = B + (size_t)(bn * 256 + rs) * K + cs;
  const unsigned short* agB1 = agB0 + (size_t)128 * K;
  const int ldst = tid * 8;

  // fragment read offsets (ushort index inside one 8192-ushort matrix-buf)
  const int fr = lane & 15;
  const int q  = lane >> 4;                     // k-slot 0..3
  const int rbase = (fr >> 3) * 256 + q * 64 + (fr & 7) * 8;
  const int aOff = wr * 4096 + rbase;           // + m*512, m=0..7
  const int bOff = wc * 2048 + rbase;           // + n*512, n=0..3

  f32x4 acc[8][4] = {};
  const int NT = K >> 5;   // 64 K-tiles

  // prologue: stage tiles 0,1 into bufs 0,1
#pragma unroll
  for (int pf = 0; pf < 2; ++pf) {
    const int kof = pf << 5;
    gload_lds16(agA0 + kof, &As[pf][ldst]);
    gload_lds16(agA1 + kof, &As[pf][ldst + 4096]);
    gload_lds16(agB0 + kof, &Bs[pf][ldst]);
    gload_lds16(agB1 + kof, &Bs[pf][ldst + 4096]);
  }
  asm volatile("s_waitcnt vmcnt(4)" ::: "memory");   // tile 0 landed
  asm volatile("s_barrier" ::: "memory");

  int rb = 0;   // buf of tile t
  int sb = 2;   // buf of tile t+2
  for (int t = 0; t < NT; ++t) {
    const unsigned short* ab = &As[rb][0];
    const unsigned short* bb = &Bs[rb][0];
    const bool st = (t + 2) < NT;               // uniform
    const int kof = (t + 2) << 5;

    // ===== phase 0: A-low + B frags, stage A(t+2) =====
    bf16x8 afL[4], bf[4];
#pragma unroll
    for (int n = 0; n < 4; ++n)
      bf[n] = *reinterpret_cast<const bf16x8*>(bb + bOff + n * 512);
#pragma unroll
    for (int m = 0; m < 4; ++m)
      afL[m] = *reinterpret_cast<const bf16x8*>(ab + aOff + m * 512);
    if (st) {
      gload_lds16(agA0 + kof, &As[sb][ldst]);
      gload_lds16(agA1 + kof, &As[sb][ldst + 4096]);
    }
    __builtin_amdgcn_sched_barrier(0);
    asm volatile("s_barrier" ::: "memory");
    __builtin_amdgcn_sched_barrier(0);
    __builtin_amdgcn_s_setprio(1);
#pragma unroll
    for (int m = 0; m < 4; ++m)
#pragma unroll
      for (int n = 0; n < 4; ++n)
        acc[m][n] = __builtin_amdgcn_mfma_f32_16x16x32_bf16(afL[m], bf[n], acc[m][n], 0, 0, 0);
    __builtin_amdgcn_s_setprio(0);
    __builtin_amdgcn_sched_barrier(0);
    asm volatile("s_barrier" ::: "memory");

    // ===== phase 1: A-high frags, stage B(t+2), counted wait =====
    bf16x8 afH[4];
#pragma unroll
    for (int m = 0; m < 4; ++m)
      afH[m] = *reinterpret_cast<const bf16x8*>(ab + aOff + (4 + m) * 512);
    if (st) {
      gload_lds16(agB0 + kof, &Bs[sb][ldst]);
      gload_lds16(agB1 + kof, &Bs[sb][ldst + 4096]);
    }
    if (t < NT - 2)       asm volatile("s_waitcnt vmcnt(4)" ::: "memory");
    else if (t == NT - 2) asm volatile("s_waitcnt vmcnt(0)" ::: "memory");
    __builtin_amdgcn_sched_barrier(0);
    asm volatile("s_barrier" ::: "memory");
    __builtin_amdgcn_sched_barrier(0);
    __builtin_amdgcn_s_setprio(1);
#pragma unroll
    for (int m = 0; m < 4; ++m)
#pragma unroll
      for (int n = 0; n < 4; ++n)
        acc[4 + m][n] = __builtin_amdgcn_mfma_f32_16x16x32_bf16(afH[m], bf[n], acc[4 + m][n], 0, 0, 0);
    __builtin_amdgcn_s_setprio(0);
    __builtin_amdgcn_sched_barrier(0);
    asm volatile("s_barrier" ::: "memory");

    rb = (rb == 2) ? 0 : rb + 1;
    sb = (sb == 2) ? 0 : sb + 1;
  }

  // epilogue: C/D layout col = lane&15, row = (lane>>4)*4 + reg
  const int rBase = bm * 256 + wr * 128 + (q << 2);
  const int cBase = bn * 256 + wc * 64 + fr;
#pragma unroll
  for (int n = 0; n < 4; ++n) {
    const int col = cBase + n * 16;
    const float bv = bias[col];
#pragma unroll
    for (int m = 0; m < 8; ++m) {
      const int row = rBase + m * 16;
#pragma unroll
      for (int r = 0; r < 4; ++r) {
        float v = acc[m][n][r] + bv;
        if (OUT_F32) {
          reinterpret_cast<float*>(Cptr)[(size_t)(row + r) * N + col] = v;
        } else {
          reinterpret_cast<unsigned short*>(Cptr)[(size_t)(row + r) * N + col] = f2b(v);
        }
      }
    }
  }
}

// ---------------- attention: one block (256 thr) per (b,h) ----------------

__global__ __launch_bounds__(256)
void k_attn(const unsigned short* __restrict__ qkv,
            const unsigned short* __restrict__ relb,
            unsigned short* __restrict__ ctx)
{
  __shared__ float qL[32][68];
  __shared__ float krL[32][68];
  __shared__ float vL[32][68];
  __shared__ float SL[32][33];

  const int bh = blockIdx.x;
  const int b = bh >> 5;
  const int h = bh & 31;
  const int t = threadIdx.x;
  const int r = t >> 3;           // row 0..31
  const int d0 = (t & 7) << 3;    // d 0..56 step 8

  const unsigned short* base = qkv + (size_t)(b * 32 + r) * 6144 + h * 64 + d0;
  u16x8 uq = *reinterpret_cast<const u16x8*>(base);
  u16x8 uk = *reinterpret_cast<const u16x8*>(base + 2048);
  u16x8 uv = *reinterpret_cast<const u16x8*>(base + 4096);
  u16x8 ur = *reinterpret_cast<const u16x8*>(relb + (((size_t)(h * 32 + r)) << 6) + d0);

  float fq[8], fkr[8], fv[8];
#pragma unroll
  for (int c = 0; c < 8; ++c) {
    fq[c] = b2f(uq[c]);
    fkr[c] = b2f(uk[c]) + b2f(ur[c]);
    fv[c] = b2f(uv[c]);
  }
  *reinterpret_cast<float4*>(&qL[r][d0])      = make_float4(fq[0], fq[1], fq[2], fq[3]);
  *reinterpret_cast<float4*>(&qL[r][d0 + 4])  = make_float4(fq[4], fq[5], fq[6], fq[7]);
  *reinterpret_cast<float4*>(&krL[r][d0])     = make_float4(fkr[0], fkr[1], fkr[2], fkr[3]);
  *reinterpret_cast<float4*>(&krL[r][d0 + 4]) = make_float4(fkr[4], fkr[5], fkr[6], fkr[7]);
  *reinterpret_cast<float4*>(&vL[r][d0])      = make_float4(fv[0], fv[1], fv[2], fv[3]);
  *reinterpret_cast<float4*>(&vL[r][d0 + 4])  = make_float4(fv[4], fv[5], fv[6], fv[7]);
  __syncthreads();

  const int i = r;
  const int j0 = (t & 7) << 2;   // 4 score cols per thread
  float s0 = 0.f, s1 = 0.f, s2 = 0.f, s3 = 0.f;
#pragma unroll
  for (int d = 0; d < 64; d += 4) {
    float4 qv = *reinterpret_cast<const float4*>(&qL[i][d]);
    float4 k0 = *reinterpret_cast<const float4*>(&krL[j0 + 0][d]);
    float4 k1 = *reinterpret_cast<const float4*>(&krL[j0 + 1][d]);
    float4 k2 = *reinterpret_cast<const float4*>(&krL[j0 + 2][d]);
    float4 k3 = *reinterpret_cast<const float4*>(&krL[j0 + 3][d]);
    s0 += qv.x * k0.x + qv.y * k0.y + qv.z * k0.z + qv.w * k0.w;
    s1 += qv.x * k1.x + qv.y * k1.y + qv.z * k1.z + qv.w * k1.w;
    s2 += qv.x * k2.x + qv.y * k2.y + qv.z * k2.z + qv.w * k2.w;
    s3 += qv.x * k3.x + qv.y * k3.y + qv.z * k3.z + qv.w * k3.w;
  }
  SL[i][j0 + 0] = s0; SL[i][j0 + 1] = s1; SL[i][j0 + 2] = s2; SL[i][j0 + 3] = s3;
  __syncthreads();

  float m = SL[i][0];
#pragma unroll
  for (int jj = 1; jj < 32; ++jj) m = fmaxf(m, SL[i][jj]);
  __syncthreads();  // all max reads done before P overwrites S

  float p0 = __expf(s0 - m), p1 = __expf(s1 - m), p2 = __expf(s2 - m), p3 = __expf(s3 - m);
  SL[i][j0 + 0] = p0; SL[i][j0 + 1] = p1; SL[i][j0 + 2] = p2; SL[i][j0 + 3] = p3;
  __syncthreads();

  float den = 0.f;
#pragma unroll
  for (int jj = 0; jj < 32; ++jj) den += SL[i][jj];
  const float inv = 1.0f / den;

  float o[8] = {0.f, 0.f, 0.f, 0.f, 0.f, 0.f, 0.f, 0.f};
#pragma unroll
  for (int jj = 0; jj < 32; ++jj) {
    float pj = SL[i][jj];
    float4 v0 = *reinterpret_cast<const float4*>(&vL[jj][d0]);
    float4 v1 = *reinterpret_cast<const float4*>(&vL[jj][d0 + 4]);
    o[0] += pj * v0.x; o[1] += pj * v0.y; o[2] += pj * v0.z; o[3] += pj * v0.w;
    o[4] += pj * v1.x; o[5] += pj * v1.y; o[6] += pj * v1.z; o[7] += pj * v1.w;
  }
  u16x8 ov;
#pragma unroll
  for (int c = 0; c < 8; ++c) ov[c] = f2b(o[c] * inv);
  *reinterpret_cast<u16x8*>(ctx + (size_t)(b * 32 + i) * 2048 + h * 64 + d0) = ov;
}

// ---------------- launch ----------------

extern "C" void kernel_launch(void* const* d_in, const int* in_sizes, int n_in,
                              void* d_out, int out_size, void* d_ws, size_t ws_size,
                              hipStream_t stream) {
  const float* x   = (const float*)d_in[0];
  const float* wq  = (const float*)d_in[1];
  const float* bq  = (const float*)d_in[2];
  const float* wk  = (const float*)d_in[3];
  const float* bk  = (const float*)d_in[4];
  const float* wv  = (const float*)d_in[5];
  const float* bv  = (const float*)d_in[6];
  const float* wo  = (const float*)d_in[7];
  const float* bo  = (const float*)d_in[8];
  const float* rpe = (const float*)d_in[9];

  char* ws = (char*)d_ws;
  unsigned short* xb    = (unsigned short*)(ws);
  unsigned short* wqkvb = (unsigned short*)(ws + 67108864);
  unsigned short* wob   = (unsigned short*)(ws + 67108864 + 25165824);
  unsigned short* qkvb  = (unsigned short*)(ws + 67108864 + 25165824 + 8388608);
  float*          bqkv  = (float*)(ws + 67108864 + 25165824 + 8388608 + 201326592);
  unsigned short* relb  = (unsigned short*)(ws + 67108864 + 25165824 + 8388608 + 201326592 + 24576);

  k_cast_f32_bf16<<<32768, 256, 0, stream>>>(x, xb, 8388608);          // 16384*2048/4
  k_build_wqkv<<<12288, 256, 0, stream>>>(wq, wk, wv, wqkvb);
  k_cast_f32_bf16<<<4096, 256, 0, stream>>>(wo, wob, 1048576);         // 2048*2048/4
  k_build_bqkv<<<24, 256, 0, stream>>>(bq, bk, bv, bqkv);
  k_build_rel<<<64, 256, 0, stream>>>(rpe, relb);

  // QKV projection: [16384][6144] = xb * wqkvb^T + bqkv  (bf16 out); grid 64x24=1536 (%8==0)
  k_gemm256<0><<<(16384 / 256) * (6144 / 256), 512, 0, stream>>>(
      xb, wqkvb, bqkv, qkvb, 16384, 6144, 2048);

  // attention -> ctx (reuses xb buffer)
  k_attn<<<16384, 256, 0, stream>>>(qkvb, relb, xb);

  // output projection: [16384][2048] = ctx * wob^T + bo  (fp32 out); grid 64x8=512 (%8==0)
  k_gemm256<1><<<(16384 / 256) * (2048 / 256), 512, 0, stream>>>(
      xb, wob, bo, (float*)d_out, 16384, 2048, 2048);
}